// Round 1
// baseline (1029.985 us; speedup 1.0000x reference)
//
#include <hip/hip_runtime.h>
#include <stdint.h>

typedef int v4i __attribute__((ext_vector_type(4)));

#define MDIM 16384   // B*S = 4*4096
#define NDIM 8192    // D_OUT
#define KDIM 2048    // D_IN

// ---------------------------------------------------------------------------
// Kernel 1: partial sums of |w| in double (deterministic tree reduction).
// ---------------------------------------------------------------------------
__global__ __launch_bounds__(256) void absw_partial_kernel(
    const float* __restrict__ w, double* __restrict__ part) {
  const float4* wv = (const float4*)w;
  const int t = threadIdx.x;
  const int tid = blockIdx.x * 256 + t;
  double s = 0.0;
#pragma unroll
  for (int i = 0; i < 8; ++i) {
    float4 v = wv[tid + i * (2048 * 256)];
    s += (double)fabsf(v.x) + (double)fabsf(v.y) +
         (double)fabsf(v.z) + (double)fabsf(v.w);
  }
  __shared__ double red[256];
  red[t] = s;
  __syncthreads();
  for (int off = 128; off > 0; off >>= 1) {
    if (t < off) red[t] += red[t + off];
    __syncthreads();
  }
  if (t == 0) part[blockIdx.x] = red[0];
}

// ---------------------------------------------------------------------------
// Kernel 2: reduce 2048 partials -> fp32 weight scale = clip(mean|w|, 1e-8).
// ---------------------------------------------------------------------------
__global__ __launch_bounds__(256) void absw_finalize_kernel(
    const double* __restrict__ part, float* __restrict__ wscale) {
  const int t = threadIdx.x;
  double s = 0.0;
#pragma unroll
  for (int i = 0; i < 8; ++i) s += part[t + i * 256];
  __shared__ double red[256];
  red[t] = s;
  __syncthreads();
  for (int off = 128; off > 0; off >>= 1) {
    if (t < off) red[t] += red[t + off];
    __syncthreads();
  }
  if (t == 0) {
    double mean = red[0] / 16777216.0;
    float sc = (float)mean;
    if (sc < 1e-8f) sc = 1e-8f;
    wscale[0] = sc;
  }
}

// ---------------------------------------------------------------------------
// Kernel 3: ternarize weights: q = clip(rint(w/scale), -1, 1) as int8.
// ---------------------------------------------------------------------------
__global__ __launch_bounds__(256) void quant_w_kernel(
    const float* __restrict__ w, const float* __restrict__ wscale,
    uint32_t* __restrict__ qw) {
  const int idx = blockIdx.x * 256 + threadIdx.x;  // 0..4194303
  const float s = wscale[0];
  float4 v = ((const float4*)w)[idx];
  int q0 = (int)fminf(fmaxf(rintf(v.x / s), -1.f), 1.f);
  int q1 = (int)fminf(fmaxf(rintf(v.y / s), -1.f), 1.f);
  int q2 = (int)fminf(fmaxf(rintf(v.z / s), -1.f), 1.f);
  int q3 = (int)fminf(fmaxf(rintf(v.w / s), -1.f), 1.f);
  uint32_t p = (uint32_t)(uint8_t)(int8_t)q0 |
               ((uint32_t)(uint8_t)(int8_t)q1 << 8) |
               ((uint32_t)(uint8_t)(int8_t)q2 << 16) |
               ((uint32_t)(uint8_t)(int8_t)q3 << 24);
  qw[idx] = p;
}

// ---------------------------------------------------------------------------
// Kernel 4: RMSNorm + activation quant. One block (256 thr) per row of 2048.
// ---------------------------------------------------------------------------
__global__ __launch_bounds__(256) void rms_quant_x_kernel(
    const float* __restrict__ x, const float* __restrict__ gamma,
    uint64_t* __restrict__ qa, float* __restrict__ rowscale) {
  const int row = blockIdx.x;
  const int t = threadIdx.x;
  const float4* xr = (const float4*)(x + (size_t)row * KDIM);
  float4 v0 = xr[t * 2];
  float4 v1 = xr[t * 2 + 1];
  float xs[8] = {v0.x, v0.y, v0.z, v0.w, v1.x, v1.y, v1.z, v1.w};
  float ss = 0.f;
#pragma unroll
  for (int i = 0; i < 8; ++i) ss += xs[i] * xs[i];

  __shared__ float red[256];
  red[t] = ss;
  __syncthreads();
  for (int off = 128; off > 0; off >>= 1) {
    if (t < off) red[t] += red[t + off];
    __syncthreads();
  }
  const float rstd = rsqrtf(red[0] / 2048.0f + 1e-6f);

  const float4* gr = (const float4*)gamma;
  float4 g0 = gr[t * 2];
  float4 g1 = gr[t * 2 + 1];
  float gs[8] = {g0.x, g0.y, g0.z, g0.w, g1.x, g1.y, g1.z, g1.w};
  float xn[8];
  float am = 0.f;
#pragma unroll
  for (int i = 0; i < 8; ++i) {
    xn[i] = xs[i] * rstd * gs[i];
    am = fmaxf(am, fabsf(xn[i]));
  }
  __syncthreads();  // done reading red[0] from sum phase
  red[t] = am;
  __syncthreads();
  for (int off = 128; off > 0; off >>= 1) {
    if (t < off) red[t] = fmaxf(red[t], red[t + off]);
    __syncthreads();
  }
  const float amax = fmaxf(red[0], 1e-5f);
  const float scale = 127.0f / amax;

  uint64_t p = 0;
#pragma unroll
  for (int i = 0; i < 8; ++i) {
    int q = (int)fminf(fmaxf(rintf(xn[i] * scale), -128.f), 127.f);
    p |= (uint64_t)(uint8_t)(int8_t)q << (8 * i);
  }
  qa[(size_t)row * 256 + t] = p;
  if (t == 0) rowscale[row] = 1.0f / scale;
}

// ---------------------------------------------------------------------------
// Kernel 5: int8 x ternary GEMM, 256x256 tile, BK=64, 8 waves (2Mx4N),
// 4-deep LDS ring (128 KiB), counted vmcnt(8), raw s_barrier (no drain),
// setprio around MFMA, XOR chunk swizzle, bijective XCD block swizzle.
// C[m][n] = rowscale[m] * sum_k qa[m][k]*qw[n][k]
// ---------------------------------------------------------------------------
#define BK 64
#define NT (KDIM / BK)  // 32

// stage A (or B) of K-tile T into ring slot (T&3): 2 global_load_lds/thread,
// 512 threads x 16B x 2 = 16 KB = 256 rows x 64 B.
#define STAGE_A(T)                                                            \
  {                                                                           \
    const int so_ = ((T) & 3) << 14;                                          \
    const int ko_ = (T) * BK;                                                 \
    __builtin_amdgcn_global_load_lds(                                         \
        (const __attribute__((address_space(1))) void*)(gA0 + ko_),           \
        (__attribute__((address_space(3))) void*)(smA + so_ + w * 1024), 16,  \
        0, 0);                                                                \
    __builtin_amdgcn_global_load_lds(                                         \
        (const __attribute__((address_space(1))) void*)(gA1 + ko_),           \
        (__attribute__((address_space(3))) void*)(smA + so_ + 8192 +          \
                                                  w * 1024),                  \
        16, 0, 0);                                                            \
  }
#define STAGE_B(T)                                                            \
  {                                                                           \
    const int so_ = ((T) & 3) << 14;                                          \
    const int ko_ = (T) * BK;                                                 \
    __builtin_amdgcn_global_load_lds(                                         \
        (const __attribute__((address_space(1))) void*)(gB0 + ko_),           \
        (__attribute__((address_space(3))) void*)(smB + so_ + w * 1024), 16,  \
        0, 0);                                                                \
    __builtin_amdgcn_global_load_lds(                                         \
        (const __attribute__((address_space(1))) void*)(gB1 + ko_),           \
        (__attribute__((address_space(3))) void*)(smB + so_ + 8192 +          \
                                                  w * 1024),                  \
        16, 0, 0);                                                            \
  }
#define BARRIER() asm volatile("s_barrier" ::: "memory")

__global__ __launch_bounds__(512, 2) void gemm_i8_kernel(
    const int8_t* __restrict__ qa, const int8_t* __restrict__ qw,
    const float* __restrict__ rowscale, float* __restrict__ out) {
  __shared__ char smA[4 * 256 * BK];  // 64 KB ring (4 slots x 16 KB)
  __shared__ char smB[4 * 256 * BK];  // 64 KB ring

  const int tid = threadIdx.x;
  const int w = tid >> 6;   // wave 0..7
  const int l = tid & 63;
  const int wm = w >> 2;    // 0..1
  const int wn = w & 3;     // 0..3

  // bijective XCD swizzle: 2048 wgs, 8 XCDs, 256/XCD. bn fast -> A-panel reuse.
  const int b = blockIdx.x;
  const int nb = (b & 7) * 256 + (b >> 3);
  const int bm = nb >> 5;  // 0..63
  const int bn = nb & 31;  // 0..31

  // staging source: thread tid covers LDS row = li*128 + (tid>>2),
  // chunk (tid&3); pre-swizzled source column (inverse of read swizzle).
  const int srow = tid >> 2;
  const int sc = ((tid & 3) << 4) ^ (((srow >> 1) & 3) << 4);
  const int8_t* gA0 = qa + (size_t)(bm * 256 + srow) * KDIM + sc;
  const int8_t* gA1 = qa + (size_t)(bm * 256 + 128 + srow) * KDIM + sc;
  const int8_t* gB0 = qw + (size_t)(bn * 256 + srow) * KDIM + sc;
  const int8_t* gB1 = qw + (size_t)(bn * 256 + 128 + srow) * KDIM + sc;

  // fragment LDS byte offsets (swizzle-corrected): row r, chunk kc=l>>4
  const int kc = l >> 4;
  const int fr = l & 15;
  int offA[8], offB[4];
#pragma unroll
  for (int i = 0; i < 8; ++i) {
    int r = wm * 128 + i * 16 + fr;
    offA[i] = r * 64 + ((kc ^ ((r >> 1) & 3)) << 4);
  }
#pragma unroll
  for (int j = 0; j < 4; ++j) {
    int r = wn * 64 + j * 16 + fr;
    offB[j] = r * 64 + ((kc ^ ((r >> 1) & 3)) << 4);
  }

  v4i acc[8][4];
  const v4i vzero = {0, 0, 0, 0};
#pragma unroll
  for (int i = 0; i < 8; ++i)
#pragma unroll
    for (int j = 0; j < 4; ++j) acc[i][j] = vzero;

  // prologue: stage tiles 0,1,2 (12 loads/wave); wait for tile 0 (vmcnt 8).
  STAGE_A(0);
  STAGE_B(0);
  STAGE_A(1);
  STAGE_B(1);
  STAGE_A(2);
  STAGE_B(2);
  asm volatile("s_waitcnt vmcnt(8)" ::: "memory");
  BARRIER();

  // main loop: tiles 0..NT-4; stages tile t+3; vmcnt(8) once per tile.
  for (int t = 0; t < NT - 3; ++t) {
    const int so = (t & 3) << 14;
    v4i af[4], bf[4];
    // ---- phase 0: all B frags + A frags (rows 0..63 of wave half) ----
#pragma unroll
    for (int j = 0; j < 4; ++j) bf[j] = *(const v4i*)(smB + so + offB[j]);
#pragma unroll
    for (int i = 0; i < 4; ++i) af[i] = *(const v4i*)(smA + so + offA[i]);
    STAGE_A(t + 3);
    BARRIER();
    __builtin_amdgcn_s_setprio(1);
#pragma unroll
    for (int i = 0; i < 4; ++i)
#pragma unroll
      for (int j = 0; j < 4; ++j)
        acc[i][j] = __builtin_amdgcn_mfma_i32_16x16x64_i8(af[i], bf[j],
                                                          acc[i][j], 0, 0, 0);
    __builtin_amdgcn_s_setprio(0);
    BARRIER();
    // ---- phase 1: A frags (rows 64..127); B frags reused from regs ----
#pragma unroll
    for (int i = 0; i < 4; ++i) af[i] = *(const v4i*)(smA + so + offA[4 + i]);
    STAGE_B(t + 3);
    asm volatile("s_waitcnt vmcnt(8)" ::: "memory");  // tile t+1 landed
    BARRIER();
    __builtin_amdgcn_s_setprio(1);
#pragma unroll
    for (int i = 0; i < 4; ++i)
#pragma unroll
      for (int j = 0; j < 4; ++j)
        acc[4 + i][j] = __builtin_amdgcn_mfma_i32_16x16x64_i8(
            af[i], bf[j], acc[4 + i][j], 0, 0, 0);
    __builtin_amdgcn_s_setprio(0);
    BARRIER();
  }

  // tail: drain once, then 3 tiles of pure compute (all data resident).
  asm volatile("s_waitcnt vmcnt(0)" ::: "memory");
  BARRIER();
  for (int t = NT - 3; t < NT; ++t) {
    const int so = (t & 3) << 14;
    v4i af[4], bf[4];
#pragma unroll
    for (int j = 0; j < 4; ++j) bf[j] = *(const v4i*)(smB + so + offB[j]);
#pragma unroll
    for (int i = 0; i < 4; ++i) af[i] = *(const v4i*)(smA + so + offA[i]);
#pragma unroll
    for (int i = 0; i < 4; ++i)
#pragma unroll
      for (int j = 0; j < 4; ++j)
        acc[i][j] = __builtin_amdgcn_mfma_i32_16x16x64_i8(af[i], bf[j],
                                                          acc[i][j], 0, 0, 0);
#pragma unroll
    for (int i = 0; i < 4; ++i) af[i] = *(const v4i*)(smA + so + offA[4 + i]);
#pragma unroll
    for (int i = 0; i < 4; ++i)
#pragma unroll
      for (int j = 0; j < 4; ++j)
        acc[4 + i][j] = __builtin_amdgcn_mfma_i32_16x16x64_i8(
            af[i], bf[j], acc[4 + i][j], 0, 0, 0);
  }

  // epilogue: C/D layout col = l&15, row = (l>>4)*4 + reg
#pragma unroll
  for (int i = 0; i < 8; ++i) {
    const int gm0 = bm * 256 + wm * 128 + i * 16 + (l >> 4) * 4;
    const int gn0 = bn * 256 + wn * 64 + (l & 15);
#pragma unroll
    for (int r = 0; r < 4; ++r) {
      const float s = rowscale[gm0 + r];
      float* orow = out + (size_t)(gm0 + r) * NDIM + gn0;
#pragma unroll
      for (int j = 0; j < 4; ++j) orow[j * 16] = s * (float)acc[i][j][r];
    }
  }
}

// ---------------------------------------------------------------------------
extern "C" void kernel_launch(void* const* d_in, const int* in_sizes, int n_in,
                              void* d_out, int out_size, void* d_ws,
                              size_t ws_size, hipStream_t stream) {
  const float* x = (const float*)d_in[0];       // 16384*2048
  const float* weight = (const float*)d_in[1];  // 8192*2048
  const float* gamma = (const float*)d_in[2];   // 2048
  float* out = (float*)d_out;                   // 16384*8192

  char* ws = (char*)d_ws;
  int8_t* qw = (int8_t*)ws;                          // 16777216 B
  int8_t* qa = (int8_t*)(ws + 16777216);             // 33554432 B
  float* rowfac = (float*)(ws + 50331648);           // 65536 B
  double* part = (double*)(ws + 50397184);           // 16384 B
  float* wscale = (float*)(ws + 50397184 + 16384);   // 4 B

  absw_partial_kernel<<<2048, 256, 0, stream>>>(weight, part);
  absw_finalize_kernel<<<1, 256, 0, stream>>>(part, wscale);
  quant_w_kernel<<<16384, 256, 0, stream>>>(weight, wscale, (uint32_t*)qw);
  rms_quant_x_kernel<<<16384, 256, 0, stream>>>(x, gamma, (uint64_t*)qa,
                                                rowfac);
  gemm_i8_kernel<<<dim3(2048), 512, 0, stream>>>(qa, qw, rowfac, out);
}